// Round 1
// baseline (395.460 us; speedup 1.0000x reference)
//
#include <hip/hip_runtime.h>

#define DI __device__ __forceinline__

typedef __attribute__((ext_vector_type(8))) short s16x8;
typedef __attribute__((ext_vector_type(4))) float f32x4;

// fp32 -> bf16 (round to nearest even), bit pattern as ushort
DI unsigned short f2bf(float f){
  unsigned u = __float_as_uint(f);
  u = (u + 0x7FFFu + ((u >> 16) & 1u)) >> 16;
  return (unsigned short)u;
}
DI float bf2f(unsigned short h){
  return __uint_as_float(((unsigned)h) << 16);
}

// ---------------- elementwise fp32 -> bf16 ----------------
__global__ void cvt_kernel(const float* __restrict__ in, unsigned short* __restrict__ out, int n8){
  int i = blockIdx.x * blockDim.x + threadIdx.x;
  if (i >= n8) return;
  const float4* p = (const float4*)in + (size_t)i * 2;
  float4 a = p[0], b = p[1];
  s16x8 o;
  o[0] = (short)f2bf(a.x); o[1] = (short)f2bf(a.y); o[2] = (short)f2bf(a.z); o[3] = (short)f2bf(a.w);
  o[4] = (short)f2bf(b.x); o[5] = (short)f2bf(b.y); o[6] = (short)f2bf(b.z); o[7] = (short)f2bf(b.w);
  ((s16x8*)out)[i] = o;
}

// ---------------- transpose + convert: in fp32 [R][C] -> out bf16 [C][R] ----------------
__global__ void transpose_cvt(const float* __restrict__ in, unsigned short* __restrict__ out, int R, int C){
  __shared__ float t[32][33];
  int c0 = blockIdx.x * 32, r0 = blockIdx.y * 32;
  int tx = threadIdx.x, ty = threadIdx.y; // 32 x 8
  #pragma unroll
  for (int i = 0; i < 4; i++)
    t[ty + i*8][tx] = in[(size_t)(r0 + ty + i*8) * C + c0 + tx];
  __syncthreads();
  #pragma unroll
  for (int i = 0; i < 4; i++)
    out[(size_t)(c0 + ty + i*8) * R + r0 + tx] = f2bf(t[tx][ty + i*8]);
}

// ---------------- GEMM: C[M x N] = A[M x K] * Wt[N x K]^T + bias ----------------
// MODE 0: qkv GEMM, epilogue routes to q_buf / k_buf / v_t (bf16)
// MODE 1: proj GEMM, epilogue writes fp32 out
template<int MODE>
__global__ void gemm_kernel(const unsigned short* __restrict__ A,
                            const unsigned short* __restrict__ Wt,
                            const float* __restrict__ bias,
                            int N,
                            unsigned short* __restrict__ qb,
                            unsigned short* __restrict__ kb,
                            unsigned short* __restrict__ vt,
                            float* __restrict__ out)
{
  const int K = 1024;
  __shared__ unsigned short As[128 * 72]; // 128 rows x (64+8 pad)
  __shared__ unsigned short Bs[128 * 72];
  int m0 = blockIdx.y * 128, n0 = blockIdx.x * 128;
  int tid = threadIdx.x;
  int lane = tid & 63, wid = tid >> 6;
  int wm = (wid >> 1) * 64, wn = (wid & 1) * 64;
  int row_l = lane & 15, kgrp = lane >> 4;

  f32x4 acc[4][4];
  #pragma unroll
  for (int i = 0; i < 4; i++)
    #pragma unroll
    for (int j = 0; j < 4; j++)
      acc[i][j] = (f32x4){0.f, 0.f, 0.f, 0.f};

  for (int k0 = 0; k0 < K; k0 += 64){
    #pragma unroll
    for (int i = 0; i < 4; i++){
      int cid = tid + i * 256;
      int r = cid >> 3, c = (cid & 7) * 8;
      *(s16x8*)&As[r * 72 + c] = *(const s16x8*)&A [(size_t)(m0 + r) * K + k0 + c];
      *(s16x8*)&Bs[r * 72 + c] = *(const s16x8*)&Wt[(size_t)(n0 + r) * K + k0 + c];
    }
    __syncthreads();
    #pragma unroll
    for (int kc = 0; kc < 2; kc++){
      s16x8 af[4], bfr[4];
      #pragma unroll
      for (int mi = 0; mi < 4; mi++)
        af[mi] = *(const s16x8*)&As[(wm + mi*16 + row_l) * 72 + kc*32 + kgrp*8];
      #pragma unroll
      for (int ni = 0; ni < 4; ni++)
        bfr[ni] = *(const s16x8*)&Bs[(wn + ni*16 + row_l) * 72 + kc*32 + kgrp*8];
      #pragma unroll
      for (int mi = 0; mi < 4; mi++)
        #pragma unroll
        for (int ni = 0; ni < 4; ni++)
          acc[mi][ni] = __builtin_amdgcn_mfma_f32_16x16x32_bf16(af[mi], bfr[ni], acc[mi][ni], 0, 0, 0);
    }
    __syncthreads();
  }

  // epilogue: C/D layout col = lane&15, row = (lane>>4)*4 + j
  #pragma unroll
  for (int mi = 0; mi < 4; mi++){
    #pragma unroll
    for (int ni = 0; ni < 4; ni++){
      #pragma unroll
      for (int j = 0; j < 4; j++){
        int gr = m0 + wm + mi*16 + kgrp*4 + j;
        int gc = n0 + wn + ni*16 + row_l;
        float v = acc[mi][ni][j] + bias[gc];
        if (MODE == 0){
          int h = gc / 192, cc = gc % 192;
          int b = gr >> 11, s = gr & 2047;
          unsigned short bv = f2bf(v);
          if (cc < 64)        qb[(size_t)gr * 1024 + h*64 + cc] = bv;
          else if (cc < 128)  kb[(size_t)gr * 1024 + h*64 + (cc - 64)] = bv;
          else                vt[((size_t)(b*16 + h) * 64 + (cc - 128)) * 2048 + s] = bv;
        } else {
          out[(size_t)gr * N + gc] = v;
        }
      }
    }
  }
}

// ---------------- V suffix sums: sufv[b][h][t][d] = sum_{s >= t*128} v, t in [0,16] ----------------
__global__ void sufv_kernel(const unsigned short* __restrict__ vt, float* __restrict__ sufv){
  int bh = blockIdx.x;       // 32 = B*H
  int d = threadIdx.x;       // 64
  const unsigned short* row = vt + (size_t)(bh * 64 + d) * 2048;
  float acc = 0.f;
  sufv[(bh * 17 + 16) * 64 + d] = 0.f;
  for (int t = 15; t >= 0; t--){
    #pragma unroll 4
    for (int c = 15; c >= 0; c--){
      s16x8 v = *(const s16x8*)&row[t * 128 + c * 8];
      #pragma unroll
      for (int e = 0; e < 8; e++) acc += bf2f((unsigned short)v[e]);
    }
    sufv[(bh * 17 + t) * 64 + d] = acc;
  }
}

// ---------------- fused attention with head-axis softmax ----------------
// grid: 256 blocks = (b, 16-row q tile). 8 waves (512 thr).
// Per 128-key tile: wave w owns key-column octant [w*16, w*16+16).
//   phase A: for all 16 heads, 16x16 score tile via 2 MFMAs -> in-register head softmax
//            (masked (k>q) -> exactly 1/16) -> bf16 weights to LDS
//   phase B: wave w does PV for heads {2w, 2w+1} (K=128 keys, 4 MFMA k-steps)
// Fully-masked tail tiles contribute (1/16) * suffix sum of V (precomputed).
__launch_bounds__(512, 1)
__global__ void attn_kernel(const unsigned short* __restrict__ qb,
                            const unsigned short* __restrict__ kb,
                            const unsigned short* __restrict__ vt,
                            const float* __restrict__ sufv,
                            unsigned short* __restrict__ ab)
{
  extern __shared__ unsigned short lds[];
  unsigned short* Qs = lds;              // [16 rows][1032]  (1024 + 8 pad)
  unsigned short* Ws = lds + 16 * 1032;  // [16 heads * 16 q][136] (128 + 8 pad)

  int blk = blockIdx.x;
  int b = blk >> 7;
  int q0 = (blk & 127) * 16;
  int tid = threadIdx.x;
  int lane = tid & 63, w = tid >> 6;
  int row_l = lane & 15, kgrp = lane >> 4;

  // stage Q rows (all heads) to LDS
  #pragma unroll
  for (int i = 0; i < 4; i++){
    int cid = tid + i * 512;              // 2048 chunks of 8
    int r = cid >> 7, c = (cid & 127) * 8;
    *(s16x8*)&Qs[r * 1032 + c] = *(const s16x8*)&qb[(size_t)(b*2048 + q0 + r) * 1024 + c];
  }
  __syncthreads();

  f32x4 pv[2][4];
  #pragma unroll
  for (int i = 0; i < 2; i++)
    #pragma unroll
    for (int j = 0; j < 4; j++)
      pv[i][j] = (f32x4){0.f, 0.f, 0.f, 0.f};

  int nkt = q0 / 128 + 1;
  for (int kt = 0; kt < nkt; kt++){
    int k0 = kt * 128;
    int key = k0 + w * 16 + row_l;

    // ---- phase A: scores for all 16 heads, this wave's 16-key octant ----
    f32x4 sc[16];
    #pragma unroll
    for (int h = 0; h < 16; h++){
      f32x4 a = (f32x4){0.f, 0.f, 0.f, 0.f};
      #pragma unroll
      for (int kc = 0; kc < 2; kc++){
        s16x8 qf = *(const s16x8*)&Qs[row_l * 1032 + h*64 + kc*32 + kgrp*8];
        s16x8 kf = *(const s16x8*)&kb[(size_t)(b*2048 + key) * 1024 + h*64 + kc*32 + kgrp*8];
        a = __builtin_amdgcn_mfma_f32_16x16x32_bf16(qf, kf, a, 0, 0, 0);
      }
      sc[h] = a;
    }

    __syncthreads();  // previous phase B finished reading Ws

    // ---- head-axis softmax, in-register (per element: 16 head values) ----
    #pragma unroll
    for (int j = 0; j < 4; j++){
      int qr = kgrp * 4 + j;
      bool masked = key > (q0 + qr);
      float m = sc[0][j];
      #pragma unroll
      for (int h = 1; h < 16; h++) m = fmaxf(m, sc[h][j]);
      float p[16]; float ssum = 0.f;
      #pragma unroll
      for (int h = 0; h < 16; h++){ p[h] = __expf(sc[h][j] - m); ssum += p[h]; }
      float inv = 1.f / ssum;
      #pragma unroll
      for (int h = 0; h < 16; h++){
        float wv = masked ? 0.0625f : p[h] * inv;
        Ws[(h*16 + qr) * 136 + w*16 + row_l] = f2bf(wv);
      }
    }
    __syncthreads();  // Ws visible to all waves

    // ---- phase B: PV for this wave's 2 heads ----
    #pragma unroll
    for (int hh = 0; hh < 2; hh++){
      int h2 = w * 2 + hh;
      #pragma unroll
      for (int kc = 0; kc < 4; kc++){
        s16x8 afr = *(const s16x8*)&Ws[(h2*16 + row_l) * 136 + kc*32 + kgrp*8];
        #pragma unroll
        for (int dq = 0; dq < 4; dq++){
          s16x8 vf = *(const s16x8*)&vt[((size_t)(b*16 + h2) * 64 + dq*16 + row_l) * 2048 + k0 + kc*32 + kgrp*8];
          pv[hh][dq] = __builtin_amdgcn_mfma_f32_16x16x32_bf16(afr, vf, pv[hh][dq], 0, 0, 0);
        }
      }
    }
  }

  // ---- epilogue: add (1/16) * V suffix, write a (bf16) ----
  int tsuf = nkt; // = q0/128 + 1
  #pragma unroll
  for (int hh = 0; hh < 2; hh++){
    int h2 = w * 2 + hh;
    #pragma unroll
    for (int dq = 0; dq < 4; dq++){
      float suf = sufv[((b*16 + h2) * 17 + tsuf) * 64 + dq*16 + row_l];
      #pragma unroll
      for (int j = 0; j < 4; j++){
        float val = pv[hh][dq][j] + 0.0625f * suf;
        ab[(size_t)(b*2048 + q0 + kgrp*4 + j) * 1024 + h2*64 + dq*16 + row_l] = f2bf(val);
      }
    }
  }
}

// ---------------- host ----------------
extern "C" void kernel_launch(void* const* d_in, const int* in_sizes, int n_in,
                              void* d_out, int out_size, void* d_ws, size_t ws_size,
                              hipStream_t stream) {
  (void)in_sizes; (void)n_in; (void)out_size; (void)ws_size;
  const float* x  = (const float*)d_in[0];
  const float* Wa = (const float*)d_in[1];
  const float* ba = (const float*)d_in[2];
  const float* Wp = (const float*)d_in[3];
  const float* bp = (const float*)d_in[4];
  float* out = (float*)d_out;

  char* ws = (char*)d_ws;
  size_t off = 0;
  auto alloc = [&](size_t bytes) -> void* {
    void* p = ws + off;
    off += (bytes + 255) & ~(size_t)255;
    return p;
  };
  unsigned short* xb   = (unsigned short*)alloc((size_t)4096*1024*2); // x bf16
  unsigned short* WaT  = (unsigned short*)alloc((size_t)3072*1024*2); // W_atten^T bf16 [N][K]
  unsigned short* WpT  = (unsigned short*)alloc((size_t)1024*1024*2); // W_proj^T bf16 [N][K]
  unsigned short* qbuf = (unsigned short*)alloc((size_t)4096*1024*2); // q [b*s][h*64+d]
  unsigned short* kbuf = (unsigned short*)alloc((size_t)4096*1024*2); // k [b*s][h*64+d]
  unsigned short* vt   = (unsigned short*)alloc((size_t)4096*1024*2); // v^T [b*16+h][d][s]
  unsigned short* abuf = (unsigned short*)alloc((size_t)4096*1024*2); // attn out bf16
  float* sufv          = (float*)alloc((size_t)32*17*64*4);           // V suffix sums

  // 1) conversions
  cvt_kernel<<<2048, 256, 0, stream>>>(x, xb, 4096*1024/8);
  transpose_cvt<<<dim3(3072/32, 1024/32), dim3(32, 8), 0, stream>>>(Wa, WaT, 1024, 3072);
  transpose_cvt<<<dim3(1024/32, 1024/32), dim3(32, 8), 0, stream>>>(Wp, WpT, 1024, 1024);

  // 2) QKV GEMM -> q/k/v buffers
  gemm_kernel<0><<<dim3(3072/128, 4096/128), 256, 0, stream>>>(xb, WaT, ba, 3072, qbuf, kbuf, vt, nullptr);

  // 3) V suffix sums
  sufv_kernel<<<32, 64, 0, stream>>>(vt, sufv);

  // 4) fused attention
  static int smem_set = 0;
  size_t smem = (16*1032 + 16*16*136) * sizeof(unsigned short); // 102656
  if (!smem_set) {
    hipFuncSetAttribute(reinterpret_cast<const void*>(attn_kernel),
                        hipFuncAttributeMaxDynamicSharedMemorySize, (int)smem);
    smem_set = 1;
  }
  attn_kernel<<<256, 512, smem, stream>>>(qbuf, kbuf, vt, sufv, abuf);

  // 5) projection GEMM -> out (fp32)
  gemm_kernel<1><<<dim3(1024/128, 4096/128), 256, 0, stream>>>(abuf, WpT, bp, 1024, nullptr, nullptr, nullptr, out);
}

// Round 2
// 286.755 us; speedup vs baseline: 1.3791x; 1.3791x over previous
//
#include <hip/hip_runtime.h>

#define DI __device__ __forceinline__

typedef __attribute__((ext_vector_type(8))) short s16x8;
typedef __attribute__((ext_vector_type(4))) short s16x4;
typedef __attribute__((ext_vector_type(4))) float f32x4;

// fp32 -> bf16 (round to nearest even), bit pattern as ushort
DI unsigned short f2bf(float f){
  unsigned u = __float_as_uint(f);
  u = (u + 0x7FFFu + ((u >> 16) & 1u)) >> 16;
  return (unsigned short)u;
}
DI float bf2f(unsigned short h){
  return __uint_as_float(((unsigned)h) << 16);
}

// ---------------- elementwise fp32 -> bf16 ----------------
__global__ void cvt_kernel(const float* __restrict__ in, unsigned short* __restrict__ out, int n8){
  int i = blockIdx.x * blockDim.x + threadIdx.x;
  if (i >= n8) return;
  const float4* p = (const float4*)in + (size_t)i * 2;
  float4 a = p[0], b = p[1];
  s16x8 o;
  o[0] = (short)f2bf(a.x); o[1] = (short)f2bf(a.y); o[2] = (short)f2bf(a.z); o[3] = (short)f2bf(a.w);
  o[4] = (short)f2bf(b.x); o[5] = (short)f2bf(b.y); o[6] = (short)f2bf(b.z); o[7] = (short)f2bf(b.w);
  ((s16x8*)out)[i] = o;
}

// ---------------- transpose + convert: in fp32 [R][C] -> out bf16 [C][R] ----------------
__global__ void transpose_cvt(const float* __restrict__ in, unsigned short* __restrict__ out, int R, int C){
  __shared__ float t[32][33];
  int c0 = blockIdx.x * 32, r0 = blockIdx.y * 32;
  int tx = threadIdx.x, ty = threadIdx.y; // 32 x 8
  #pragma unroll
  for (int i = 0; i < 4; i++)
    t[ty + i*8][tx] = in[(size_t)(r0 + ty + i*8) * C + c0 + tx];
  __syncthreads();
  #pragma unroll
  for (int i = 0; i < 4; i++)
    out[(size_t)(c0 + ty + i*8) * R + r0 + tx] = f2bf(t[tx][ty + i*8]);
}

// ---------------- GEMM: C[M x N] = A[M x K] * Wt[N x K]^T + bias ----------------
// MODE 0: qkv GEMM, epilogue routes to q_buf (row layout), K tiled, V tiled
// MODE 1: proj GEMM, epilogue writes fp32 out
template<int MODE>
__global__ void gemm_kernel(const unsigned short* __restrict__ A,
                            const unsigned short* __restrict__ Wt,
                            const float* __restrict__ bias,
                            int N,
                            unsigned short* __restrict__ qb,
                            unsigned short* __restrict__ kb,
                            unsigned short* __restrict__ vt,
                            float* __restrict__ out)
{
  const int K = 1024;
  __shared__ unsigned short As[128 * 72]; // 128 rows x (64+8 pad)
  __shared__ unsigned short Bs[128 * 72];
  int m0 = blockIdx.y * 128, n0 = blockIdx.x * 128;
  int tid = threadIdx.x;
  int lane = tid & 63, wid = tid >> 6;
  int wm = (wid >> 1) * 64, wn = (wid & 1) * 64;
  int row_l = lane & 15, kgrp = lane >> 4;

  f32x4 acc[4][4];
  #pragma unroll
  for (int i = 0; i < 4; i++)
    #pragma unroll
    for (int j = 0; j < 4; j++)
      acc[i][j] = (f32x4){0.f, 0.f, 0.f, 0.f};

  for (int k0 = 0; k0 < K; k0 += 64){
    #pragma unroll
    for (int i = 0; i < 4; i++){
      int cid = tid + i * 256;
      int r = cid >> 3, c = (cid & 7) * 8;
      *(s16x8*)&As[r * 72 + c] = *(const s16x8*)&A [(size_t)(m0 + r) * K + k0 + c];
      *(s16x8*)&Bs[r * 72 + c] = *(const s16x8*)&Wt[(size_t)(n0 + r) * K + k0 + c];
    }
    __syncthreads();
    #pragma unroll
    for (int kc = 0; kc < 2; kc++){
      s16x8 af[4], bfr[4];
      #pragma unroll
      for (int mi = 0; mi < 4; mi++)
        af[mi] = *(const s16x8*)&As[(wm + mi*16 + row_l) * 72 + kc*32 + kgrp*8];
      #pragma unroll
      for (int ni = 0; ni < 4; ni++)
        bfr[ni] = *(const s16x8*)&Bs[(wn + ni*16 + row_l) * 72 + kc*32 + kgrp*8];
      #pragma unroll
      for (int mi = 0; mi < 4; mi++)
        #pragma unroll
        for (int ni = 0; ni < 4; ni++)
          acc[mi][ni] = __builtin_amdgcn_mfma_f32_16x16x32_bf16(af[mi], bfr[ni], acc[mi][ni], 0, 0, 0);
    }
    __syncthreads();
  }

  // epilogue: C/D layout col = lane&15, row = (lane>>4)*4 + j
  #pragma unroll
  for (int mi = 0; mi < 4; mi++){
    #pragma unroll
    for (int ni = 0; ni < 4; ni++){
      #pragma unroll
      for (int j = 0; j < 4; j++){
        int gr = m0 + wm + mi*16 + kgrp*4 + j;
        int gc = n0 + wn + ni*16 + row_l;
        float v = acc[mi][ni][j] + bias[gc];
        if (MODE == 0){
          int h = gc / 192, cc = gc % 192;
          int b = gr >> 11, s = gr & 2047;
          unsigned short bv = f2bf(v);
          if (cc < 64)
            qb[(size_t)gr * 1024 + h*64 + cc] = bv;
          else if (cc < 128)
            kb[((size_t)(b*16 + h) * 128 + (s >> 4)) * 1024 + (s & 15) * 64 + (cc - 64)] = bv;
          else
            vt[((size_t)(b*16 + h) * 16 + (s >> 7)) * 8192 + (size_t)(cc - 128) * 128 + (s & 127)] = bv;
        } else {
          out[(size_t)gr * N + gc] = v;
        }
      }
    }
  }
}

// ---------------- V suffix sums over tiled V: sufv[b][h][t][d] = sum_{s >= t*128} v ----------------
__global__ void sufv_kernel(const unsigned short* __restrict__ vt, float* __restrict__ sufv){
  int bh = blockIdx.x;       // 32 = B*H
  int d = threadIdx.x;       // 64
  const unsigned short* base = vt + (size_t)bh * 16 * 8192 + d * 128;
  float acc = 0.f;
  sufv[(bh * 17 + 16) * 64 + d] = 0.f;
  for (int t = 15; t >= 0; t--){
    #pragma unroll 4
    for (int c = 15; c >= 0; c--){
      s16x8 v = *(const s16x8*)&base[t * 8192 + c * 8];
      #pragma unroll
      for (int e = 0; e < 8; e++) acc += bf2f((unsigned short)v[e]);
    }
    sufv[(bh * 17 + t) * 64 + d] = acc;
  }
}

// ---------------- fused attention with head-axis softmax, balanced split-K ----------------
// Work pairing: for batch b, pair i in [0,64): q-tiles qa=i (nkt_a=i/8+1 tiles) and
// qb=127-i (nkt_b=16-i/8 tiles). 17 tiles per pair, split 9/8 across two blocks.
// half 0: all of qa (final output) + first 9-nkt_a tiles of qb (partial 0)
// half 1: remaining 8 tiles of qb (partial 1)
// Per 128-key tile: wave w owns key octant [w*16, w*16+16).
//   phase A (swapped): D[key][q] = mfma(K_frag, Q_frag) for all 16 heads ->
//   in-register head softmax -> packed b64 weight writes to Ws[h][q][k].
//   phase B: wave w does PV for heads {2w, 2w+1}.
__launch_bounds__(512, 1)
__global__ void attn_kernel(const unsigned short* __restrict__ qbuf,
                            const unsigned short* __restrict__ kb,   // tiled [b][h][s/16][s%16][64]
                            const unsigned short* __restrict__ vt,   // tiled [b][h][kt][64][128]
                            const float* __restrict__ sufv,
                            unsigned short* __restrict__ ab,
                            float* __restrict__ pb)
{
  extern __shared__ unsigned short lds[];
  unsigned short* Qs = lds;              // [16 rows][1032]
  unsigned short* Ws = lds + 16 * 1032;  // [16 heads * 16 q][140]

  int blk = blockIdx.x;
  int b = blk >> 7;
  int r = blk & 127;
  int i = r >> 1, half = r & 1;
  int nkt_a = i / 8 + 1;
  int qa = i, qbt = 127 - i;
  int nkt_b = 16 - i / 8;

  int tid = threadIdx.x;
  int lane = tid & 63, w = tid >> 6;
  int row_l = lane & 15, kgrp = lane >> 4;

  auto run_seg = [&](int qt, int kt0, int kt1, int mode){
    int q0 = qt * 16;
    // stage Q rows (all heads) into LDS
    #pragma unroll
    for (int ii = 0; ii < 4; ii++){
      int cid = tid + ii * 512;            // 2048 chunks of 8 shorts
      int rr = cid >> 7, c = (cid & 127) * 8;
      *(s16x8*)&Qs[rr * 1032 + c] = *(const s16x8*)&qbuf[(size_t)(b*2048 + q0 + rr) * 1024 + c];
    }
    __syncthreads();

    f32x4 pv[2][4];
    #pragma unroll
    for (int a = 0; a < 2; a++)
      #pragma unroll
      for (int d = 0; d < 4; d++)
        pv[a][d] = (f32x4){0.f, 0.f, 0.f, 0.f};

    for (int kt = kt0; kt < kt1; kt++){
      // ---- phase A: swapped QK^T for all 16 heads ----
      const unsigned short* kbase = kb + ((size_t)(b*16) * 128 + kt*8 + w) * 1024;
      f32x4 sc[16];
      #pragma unroll
      for (int h = 0; h < 16; h++){
        f32x4 a = (f32x4){0.f, 0.f, 0.f, 0.f};
        #pragma unroll
        for (int kc = 0; kc < 2; kc++){
          s16x8 kf = *(const s16x8*)&kbase[(size_t)h * 131072 + row_l*64 + kc*32 + kgrp*8];
          s16x8 qf = *(const s16x8*)&Qs[row_l * 1032 + h*64 + kc*32 + kgrp*8];
          a = __builtin_amdgcn_mfma_f32_16x16x32_bf16(kf, qf, a, 0, 0, 0);
        }
        sc[h] = a;
      }

      __syncthreads();  // previous phase B done reading Ws

      // ---- head-axis softmax in registers; lane holds key=k0+w*16+kgrp*4+j, q=q0+row_l ----
      int keybase = kt*128 + w*16 + kgrp*4;
      #pragma unroll
      for (int j = 0; j < 4; j++){
        bool masked = (keybase + j) > (q0 + row_l);
        float m = sc[0][j];
        #pragma unroll
        for (int h = 1; h < 16; h++) m = fmaxf(m, sc[h][j]);
        float ssum = 0.f;
        #pragma unroll
        for (int h = 0; h < 16; h++){ float e = __expf(sc[h][j] - m); sc[h][j] = e; ssum += e; }
        float inv = 1.f / ssum;
        #pragma unroll
        for (int h = 0; h < 16; h++)
          sc[h][j] = masked ? 0.0625f : sc[h][j] * inv;
      }
      // packed b64 weight writes: Ws[h][q=row_l][k = w*16 + kgrp*4 + j]
      #pragma unroll
      for (int h = 0; h < 16; h++){
        s16x4 pk;
        pk[0] = (short)f2bf(sc[h][0]); pk[1] = (short)f2bf(sc[h][1]);
        pk[2] = (short)f2bf(sc[h][2]); pk[3] = (short)f2bf(sc[h][3]);
        *(s16x4*)&Ws[(h*16 + row_l) * 140 + w*16 + kgrp*4] = pk;
      }
      __syncthreads();  // Ws visible

      // ---- phase B: PV for this wave's 2 heads ----
      #pragma unroll
      for (int hh = 0; hh < 2; hh++){
        int h2 = w*2 + hh;
        const unsigned short* vb = vt + ((size_t)(b*16 + h2) * 16 + kt) * 8192;
        #pragma unroll
        for (int kc = 0; kc < 4; kc++){
          s16x8 afr = *(const s16x8*)&Ws[(h2*16 + row_l) * 140 + kc*32 + kgrp*8];
          #pragma unroll
          for (int dq = 0; dq < 4; dq++){
            s16x8 vf = *(const s16x8*)&vb[(dq*16 + row_l) * 128 + kc*32 + kgrp*8];
            pv[hh][dq] = __builtin_amdgcn_mfma_f32_16x16x32_bf16(afr, vf, pv[hh][dq], 0, 0, 0);
          }
        }
      }
    }

    // ---- epilogue: D[q=kgrp*4+j][d=dq*16+row_l] ----
    if (mode == 0){
      int tsuf = qt / 8 + 1;
      #pragma unroll
      for (int hh = 0; hh < 2; hh++){
        int h2 = w*2 + hh;
        #pragma unroll
        for (int dq = 0; dq < 4; dq++){
          float suf = sufv[((b*16 + h2) * 17 + tsuf) * 64 + dq*16 + row_l];
          #pragma unroll
          for (int j = 0; j < 4; j++){
            float val = pv[hh][dq][j] + 0.0625f * suf;
            ab[(size_t)(b*2048 + q0 + kgrp*4 + j) * 1024 + h2*64 + dq*16 + row_l] = f2bf(val);
          }
        }
      }
    } else {
      float* pr = pb + ((size_t)((b*64 + i)*2) + (mode - 1)) * 16384;
      #pragma unroll
      for (int hh = 0; hh < 2; hh++){
        int h2 = w*2 + hh;
        #pragma unroll
        for (int dq = 0; dq < 4; dq++)
          #pragma unroll
          for (int j = 0; j < 4; j++)
            pr[(kgrp*4 + j) * 1024 + h2*64 + dq*16 + row_l] = pv[hh][dq][j];
      }
    }
  };

  if (half == 0){
    run_seg(qa, 0, nkt_a, 0);
    run_seg(qbt, 0, 9 - nkt_a, 1);
  } else {
    run_seg(qbt, 9 - nkt_a, nkt_b, 2);
  }
}

// ---------------- reduce partials for the split q-tiles ----------------
// grid: 2048 blocks = (b, i, qr); 256 threads x 4 floats = 1024 cols
__global__ void reduce_kernel(const float* __restrict__ pb,
                              const float* __restrict__ sufv,
                              unsigned short* __restrict__ ab)
{
  int row = blockIdx.x;
  int b = row >> 10, rr = row & 1023;
  int i = rr >> 4, qr = rr & 15;
  int qt = 127 - i;
  int tsuf = qt / 8 + 1;
  int c = threadIdx.x * 4;
  int h = c >> 6, d = c & 63;
  const float* p0 = pb + ((size_t)(b*64 + i)*2 + 0) * 16384 + qr*1024 + c;
  const float* p1 = pb + ((size_t)(b*64 + i)*2 + 1) * 16384 + qr*1024 + c;
  float4 a = *(const float4*)p0;
  float4 bb = *(const float4*)p1;
  float4 sf = *(const float4*)&sufv[((b*16 + h) * 17 + tsuf) * 64 + d];
  unsigned short o[4];
  o[0] = f2bf(a.x + bb.x + 0.0625f * sf.x);
  o[1] = f2bf(a.y + bb.y + 0.0625f * sf.y);
  o[2] = f2bf(a.z + bb.z + 0.0625f * sf.z);
  o[3] = f2bf(a.w + bb.w + 0.0625f * sf.w);
  *(s16x4*)&ab[(size_t)(b*2048 + qt*16 + qr) * 1024 + c] = *(s16x4*)o;
}

// ---------------- host ----------------
extern "C" void kernel_launch(void* const* d_in, const int* in_sizes, int n_in,
                              void* d_out, int out_size, void* d_ws, size_t ws_size,
                              hipStream_t stream) {
  (void)in_sizes; (void)n_in; (void)out_size; (void)ws_size;
  const float* x  = (const float*)d_in[0];
  const float* Wa = (const float*)d_in[1];
  const float* ba = (const float*)d_in[2];
  const float* Wp = (const float*)d_in[3];
  const float* bp = (const float*)d_in[4];
  float* out = (float*)d_out;

  char* ws = (char*)d_ws;
  size_t off = 0;
  auto alloc = [&](size_t bytes) -> void* {
    void* p = ws + off;
    off += (bytes + 255) & ~(size_t)255;
    return p;
  };
  // pbuf (16MB) aliases xb (8MB) + WaT (6MB): both dead before attn_kernel runs.
  float* pbuf          = (float*)alloc((size_t)2*64*2*16384*4);       // 16 MB
  unsigned short* xb   = (unsigned short*)((char*)pbuf);              // x bf16 (8 MB)
  unsigned short* WaT  = (unsigned short*)((char*)pbuf + (size_t)4096*1024*2); // W_atten^T (6 MB)
  unsigned short* WpT  = (unsigned short*)alloc((size_t)1024*1024*2); // W_proj^T bf16 [N][K]
  unsigned short* qbuf = (unsigned short*)alloc((size_t)4096*1024*2); // q [b*s][h*64+d]
  unsigned short* kbuf = (unsigned short*)alloc((size_t)4096*1024*2); // K tiled
  unsigned short* vt   = (unsigned short*)alloc((size_t)4096*1024*2); // V tiled
  unsigned short* abuf = (unsigned short*)alloc((size_t)4096*1024*2); // attn out bf16
  float* sufv          = (float*)alloc((size_t)32*17*64*4);           // V suffix sums

  // 1) conversions
  cvt_kernel<<<2048, 256, 0, stream>>>(x, xb, 4096*1024/8);
  transpose_cvt<<<dim3(3072/32, 1024/32), dim3(32, 8), 0, stream>>>(Wa, WaT, 1024, 3072);
  transpose_cvt<<<dim3(1024/32, 1024/32), dim3(32, 8), 0, stream>>>(Wp, WpT, 1024, 1024);

  // 2) QKV GEMM -> q (rows) / K tiled / V tiled
  gemm_kernel<0><<<dim3(3072/128, 4096/128), 256, 0, stream>>>(xb, WaT, ba, 3072, qbuf, kbuf, vt, nullptr);

  // 3) V suffix sums
  sufv_kernel<<<32, 64, 0, stream>>>(vt, sufv);

  // 4) fused attention (balanced split-K)
  static int smem_set = 0;
  size_t smem = (16*1032 + 16*16*140) * sizeof(unsigned short); // 104704
  if (!smem_set) {
    hipFuncSetAttribute(reinterpret_cast<const void*>(attn_kernel),
                        hipFuncAttributeMaxDynamicSharedMemorySize, (int)smem);
    smem_set = 1;
  }
  attn_kernel<<<256, 512, smem, stream>>>(qbuf, kbuf, vt, sufv, abuf, pbuf);

  // 5) reduce split partials into abuf
  reduce_kernel<<<2048, 256, 0, stream>>>(pbuf, sufv, abuf);

  // 6) projection GEMM -> out (fp32)
  gemm_kernel<1><<<dim3(1024/128, 4096/128), 256, 0, stream>>>(abuf, WpT, bp, 1024, nullptr, nullptr, nullptr, out);
}

// Round 3
// 177.805 us; speedup vs baseline: 2.2241x; 1.6128x over previous
//
#include <hip/hip_runtime.h>

#define DI __device__ __forceinline__

typedef __attribute__((ext_vector_type(8))) short s16x8;
typedef __attribute__((ext_vector_type(4))) short s16x4;
typedef __attribute__((ext_vector_type(4))) float f32x4;

DI unsigned short f2bf(float f){
  unsigned u = __float_as_uint(f);
  u = (u + 0x7FFFu + ((u >> 16) & 1u)) >> 16;
  return (unsigned short)u;
}
DI float bf2f(unsigned short h){
  return __uint_as_float(((unsigned)h) << 16);
}

DI void gll16(const void* g, void* l){
  __builtin_amdgcn_global_load_lds((const __attribute__((address_space(1))) void*)g,
                                   (__attribute__((address_space(3))) void*)l, 16, 0, 0);
}

// ---------------- elementwise fp32 -> bf16 ----------------
__global__ void cvt_kernel(const float* __restrict__ in, unsigned short* __restrict__ out, int n8){
  int i = blockIdx.x * blockDim.x + threadIdx.x;
  if (i >= n8) return;
  const float4* p = (const float4*)in + (size_t)i * 2;
  float4 a = p[0], b = p[1];
  s16x8 o;
  o[0] = (short)f2bf(a.x); o[1] = (short)f2bf(a.y); o[2] = (short)f2bf(a.z); o[3] = (short)f2bf(a.w);
  o[4] = (short)f2bf(b.x); o[5] = (short)f2bf(b.y); o[6] = (short)f2bf(b.z); o[7] = (short)f2bf(b.w);
  ((s16x8*)out)[i] = o;
}

// ---------------- transpose + convert: in fp32 [R][C] -> out bf16 [C][R] ----------------
__global__ void transpose_cvt(const float* __restrict__ in, unsigned short* __restrict__ out, int R, int C){
  __shared__ float t[32][33];
  int c0 = blockIdx.x * 32, r0 = blockIdx.y * 32;
  int tx = threadIdx.x, ty = threadIdx.y; // 32 x 8
  #pragma unroll
  for (int i = 0; i < 4; i++)
    t[ty + i*8][tx] = in[(size_t)(r0 + ty + i*8) * C + c0 + tx];
  __syncthreads();
  #pragma unroll
  for (int i = 0; i < 4; i++)
    out[(size_t)(c0 + ty + i*8) * R + r0 + tx] = f2bf(t[tx][ty + i*8]);
}

// ---------------- GEMM: C[M x N] = A[M x K] * Wt[N x K]^T + bias ----------------
// MODE 0: qkv GEMM -> qbuf rows, ktile [b][h][kt64][64k][64d] swizzled, vtile [b][h][kt64][64d][64k] swizzled
// MODE 1: proj GEMM -> fp32 out
template<int MODE>
__global__ void gemm_kernel(const unsigned short* __restrict__ A,
                            const unsigned short* __restrict__ Wt,
                            const float* __restrict__ bias,
                            int N,
                            unsigned short* __restrict__ qb,
                            unsigned short* __restrict__ kb,
                            unsigned short* __restrict__ vt,
                            float* __restrict__ out)
{
  const int K = 1024;
  __shared__ unsigned short As[128 * 72];
  __shared__ unsigned short Bs[128 * 72];
  int m0 = blockIdx.y * 128, n0 = blockIdx.x * 128;
  int tid = threadIdx.x;
  int lane = tid & 63, wid = tid >> 6;
  int wm = (wid >> 1) * 64, wn = (wid & 1) * 64;
  int row_l = lane & 15, kgrp = lane >> 4;

  f32x4 acc[4][4];
  #pragma unroll
  for (int i = 0; i < 4; i++)
    #pragma unroll
    for (int j = 0; j < 4; j++)
      acc[i][j] = (f32x4){0.f, 0.f, 0.f, 0.f};

  for (int k0 = 0; k0 < K; k0 += 64){
    #pragma unroll
    for (int i = 0; i < 4; i++){
      int cid = tid + i * 256;
      int r = cid >> 3, c = (cid & 7) * 8;
      *(s16x8*)&As[r * 72 + c] = *(const s16x8*)&A [(size_t)(m0 + r) * K + k0 + c];
      *(s16x8*)&Bs[r * 72 + c] = *(const s16x8*)&Wt[(size_t)(n0 + r) * K + k0 + c];
    }
    __syncthreads();
    #pragma unroll
    for (int kc = 0; kc < 2; kc++){
      s16x8 af[4], bfr[4];
      #pragma unroll
      for (int mi = 0; mi < 4; mi++)
        af[mi] = *(const s16x8*)&As[(wm + mi*16 + row_l) * 72 + kc*32 + kgrp*8];
      #pragma unroll
      for (int ni = 0; ni < 4; ni++)
        bfr[ni] = *(const s16x8*)&Bs[(wn + ni*16 + row_l) * 72 + kc*32 + kgrp*8];
      #pragma unroll
      for (int mi = 0; mi < 4; mi++)
        #pragma unroll
        for (int ni = 0; ni < 4; ni++)
          acc[mi][ni] = __builtin_amdgcn_mfma_f32_16x16x32_bf16(af[mi], bfr[ni], acc[mi][ni], 0, 0, 0);
    }
    __syncthreads();
  }

  #pragma unroll
  for (int mi = 0; mi < 4; mi++){
    #pragma unroll
    for (int ni = 0; ni < 4; ni++){
      #pragma unroll
      for (int j = 0; j < 4; j++){
        int gr = m0 + wm + mi*16 + kgrp*4 + j;
        int gc = n0 + wn + ni*16 + row_l;
        float v = acc[mi][ni][j] + bias[gc];
        if (MODE == 0){
          int h = gc / 192, cc = gc % 192;
          int b = gr >> 11, s = gr & 2047;
          unsigned short bv = f2bf(v);
          if (cc < 64){
            qb[(size_t)gr * 1024 + h*64 + cc] = bv;
          } else if (cc < 128){
            int d = cc - 64; int kt = s >> 6, kk = s & 63;
            kb[(size_t)((b*16 + h)*32 + kt) * 4096 + ((kk*64 + d) ^ ((kk & 7) << 3))] = bv;
          } else {
            int d = cc - 128; int kt = s >> 6, kk = s & 63;
            vt[(size_t)((b*16 + h)*32 + kt) * 4096 + ((d*64 + kk) ^ ((d & 7) << 3))] = bv;
          }
        } else {
          out[(size_t)gr * N + gc] = v;
        }
      }
    }
  }
}

// ---------------- V suffix sums (64-key granularity): sufv[bh][t in 0..32][64d] ----------------
__global__ void sufv_kernel(const unsigned short* __restrict__ vt, float* __restrict__ sufv){
  __shared__ float tot[4][64];
  int bh = blockIdx.x;                 // 32
  int tid = threadIdx.x;               // 256
  int tq = tid >> 6, d = tid & 63;
  const unsigned short* base = vt + (size_t)bh * 32 * 4096;
  float s[8];
  float run = 0.f;
  for (int j = 7; j >= 0; j--){
    int t = tq*8 + j;
    float rs = 0.f;
    #pragma unroll
    for (int c = 0; c < 8; c++){
      int idx = (d*64 + c*8) ^ ((d & 7) << 3);
      s16x8 v = *(const s16x8*)&base[(size_t)t*4096 + idx];
      #pragma unroll
      for (int e = 0; e < 8; e++) rs += bf2f((unsigned short)v[e]);
    }
    run += rs; s[j] = run;
  }
  tot[tq][d] = run;
  __syncthreads();
  float carry = 0.f;
  for (int t2 = tq+1; t2 < 4; t2++) carry += tot[t2][d];
  #pragma unroll
  for (int j = 0; j < 8; j++)
    sufv[((size_t)bh*33 + tq*8 + j)*64 + d] = s[j] + carry;
  if (tid < 64) sufv[((size_t)bh*33 + 32)*64 + tid] = 0.f;
}

// ---------------- D-pass: invDT[b][k][q] = 1 / sum_h exp(s_h(q,k)) over causal triangle ----------------
// grid: 1056 = b * 528 triangle tiles of 64x64. 4 waves; wave w owns q rows [qt*64+w*16, +16).
__launch_bounds__(256)
__global__ void dpass_kernel(const unsigned short* __restrict__ qbuf,
                             const unsigned short* __restrict__ kb,
                             float* __restrict__ invDT)
{
  __shared__ unsigned short Kst[2][4096];
  int blk = blockIdx.x;
  int b = blk / 528, t = blk % 528;
  int qt = (int)((sqrtf(8.f*t + 1.f) - 1.f) * 0.5f);
  while ((qt+1)*(qt+2)/2 <= t) qt++;
  while (qt*(qt+1)/2 > t) qt--;
  int kt = t - qt*(qt+1)/2;

  int tid = threadIdx.x, lane = tid & 63, w = tid >> 6;
  int row_l = lane & 15, kgrp = lane >> 4;

  const unsigned short* ktb = kb + ((size_t)(b*16)*32 + kt) * 4096;  // + h*32*4096

  auto stage = [&](int h, int buf){
    const unsigned short* src = ktb + (size_t)h * 32 * 4096;
    #pragma unroll
    for (int c = 0; c < 2; c++)
      gll16(src + (w*128 + c*64 + lane)*8, (void*)(&Kst[buf][0] + w*1024 + c*512));
  };

  stage(0, 0);

  f32x4 esum[4];
  #pragma unroll
  for (int ks = 0; ks < 4; ks++) esum[ks] = (f32x4){0.f,0.f,0.f,0.f};

  const unsigned short* qrow_p = qbuf + (size_t)(b*2048 + qt*64 + w*16 + row_l) * 1024;
  s16x8 qf0 = *(const s16x8*)&qrow_p[kgrp*8];
  s16x8 qf1 = *(const s16x8*)&qrow_p[32 + kgrp*8];

  for (int h = 0; h < 16; h++){
    int buf = h & 1;
    s16x8 qn0, qn1;
    if (h < 15){
      qn0 = *(const s16x8*)&qrow_p[(h+1)*64 + kgrp*8];
      qn1 = *(const s16x8*)&qrow_p[(h+1)*64 + 32 + kgrp*8];
      stage(h+1, buf ^ 1);
    }
    __builtin_amdgcn_sched_barrier(0);
    if (h < 15) asm volatile("s_waitcnt vmcnt(4)" ::: "memory");
    else        asm volatile("s_waitcnt vmcnt(0)" ::: "memory");
    __builtin_amdgcn_sched_barrier(0);
    __builtin_amdgcn_s_barrier();
    __builtin_amdgcn_sched_barrier(0);

    #pragma unroll
    for (int ks = 0; ks < 4; ks++){
      int row = ks*16 + row_l;
      int e0 = (row*64 + kgrp*8) ^ ((row & 7) << 3);
      int e1 = (row*64 + 32 + kgrp*8) ^ ((row & 7) << 3);
      s16x8 a0 = *(const s16x8*)&Kst[buf][e0];
      s16x8 a1 = *(const s16x8*)&Kst[buf][e1];
      f32x4 sc = __builtin_amdgcn_mfma_f32_16x16x32_bf16(a0, qf0, (f32x4){0.f,0.f,0.f,0.f}, 0, 0, 0);
      sc = __builtin_amdgcn_mfma_f32_16x16x32_bf16(a1, qf1, sc, 0, 0, 0);
      #pragma unroll
      for (int j = 0; j < 4; j++) esum[ks][j] += __expf(sc[j]);
    }
    __builtin_amdgcn_sched_barrier(0);
    __builtin_amdgcn_s_barrier();
    if (h < 15){ qf0 = qn0; qf1 = qn1; }
  }

  // write invD transposed: [b][key][q]
  int qcol = qt*64 + w*16 + row_l;
  #pragma unroll
  for (int ks = 0; ks < 4; ks++)
    #pragma unroll
    for (int j = 0; j < 4; j++){
      int key = kt*64 + ks*16 + kgrp*4 + j;
      invDT[(size_t)b*4194304 + (size_t)key*2048 + qcol] = 1.f / esum[ks][j];
    }
}

// ---------------- PV-pass: per (b,h), w = exp(s)*invD (masked -> 1/16 via suffix), O = w @ V ----------------
// grid 1024 = (b, h, pair i, half). 4 waves; wave w owns q rows [qt*64+w*16, +16).
__launch_bounds__(256)
__global__ void pv_kernel(const unsigned short* __restrict__ qbuf,
                          const unsigned short* __restrict__ kb,
                          const unsigned short* __restrict__ vt,
                          const float* __restrict__ invDT,
                          const float* __restrict__ sufv,
                          unsigned short* __restrict__ ab,
                          float* __restrict__ pb)
{
  __shared__ unsigned short Kst[2][4096];
  __shared__ unsigned short Vst[2][4096];
  __shared__ unsigned short Ws[4][16*72];

  int blk = blockIdx.x;
  int b = blk >> 9;
  int r = blk & 511;
  int h = r >> 5;
  int r2 = r & 31;
  int i = r2 >> 1, half = r2 & 1;
  int qsm = i, qbig = 31 - i;

  int tid = threadIdx.x, lane = tid & 63, w = tid >> 6;
  int row_l = lane & 15, kgrp = lane >> 4;

  const unsigned short* KT = kb + (size_t)((b*16 + h)*32) * 4096;
  const unsigned short* VT = vt + (size_t)((b*16 + h)*32) * 4096;
  const float* invB = invDT + (size_t)b * 4194304;

  auto stage = [&](int kt, int par){
    #pragma unroll
    for (int c = 0; c < 2; c++){
      gll16(KT + (size_t)kt*4096 + (w*128 + c*64 + lane)*8, (void*)(&Kst[par][0] + w*1024 + c*512));
      gll16(VT + (size_t)kt*4096 + (w*128 + c*64 + lane)*8, (void*)(&Vst[par][0] + w*1024 + c*512));
    }
  };

  auto run = [&](int qt, int k0t, int k1t, int mode){
    int q0 = qt * 64;
    int qv = q0 + w*16 + row_l;
    const unsigned short* qrow_p = qbuf + (size_t)(b*2048 + qv) * 1024 + h*64;
    s16x8 qf0 = *(const s16x8*)&qrow_p[kgrp*8];
    s16x8 qf1 = *(const s16x8*)&qrow_p[32 + kgrp*8];

    f32x4 pv[4];
    #pragma unroll
    for (int d = 0; d < 4; d++) pv[d] = (f32x4){0.f,0.f,0.f,0.f};

    stage(k0t, 0);

    for (int kt = k0t; kt < k1t; kt++){
      int par = (kt - k0t) & 1;
      // invD loads first (older in FIFO than next-tile staging)
      float invd[4][4];
      #pragma unroll
      for (int ks = 0; ks < 4; ks++)
        #pragma unroll
        for (int j = 0; j < 4; j++){
          int key = kt*64 + ks*16 + kgrp*4 + j;
          invd[ks][j] = invB[(size_t)key*2048 + qv];
        }
      bool has_next = (kt + 1 < k1t);
      if (has_next) stage(kt+1, par ^ 1);
      __builtin_amdgcn_sched_barrier(0);
      if (has_next) asm volatile("s_waitcnt vmcnt(20)" ::: "memory");
      else          asm volatile("s_waitcnt vmcnt(16)" ::: "memory");
      __builtin_amdgcn_sched_barrier(0);
      __builtin_amdgcn_s_barrier();
      __builtin_amdgcn_sched_barrier(0);

      // QK^T (swapped: rows=key, cols=q)
      f32x4 sc[4];
      #pragma unroll
      for (int ks = 0; ks < 4; ks++){
        int row = ks*16 + row_l;
        int e0 = (row*64 + kgrp*8) ^ ((row & 7) << 3);
        int e1 = (row*64 + 32 + kgrp*8) ^ ((row & 7) << 3);
        s16x8 a0 = *(const s16x8*)&Kst[par][e0];
        s16x8 a1 = *(const s16x8*)&Kst[par][e1];
        sc[ks] = __builtin_amdgcn_mfma_f32_16x16x32_bf16(a0, qf0, (f32x4){0.f,0.f,0.f,0.f}, 0, 0, 0);
        sc[ks] = __builtin_amdgcn_mfma_f32_16x16x32_bf16(a1, qf1, sc[ks], 0, 0, 0);
      }
      // weights
      #pragma unroll
      for (int ks = 0; ks < 4; ks++){
        #pragma unroll
        for (int j = 0; j < 4; j++){
          int key = kt*64 + ks*16 + kgrp*4 + j;
          float e = __expf(sc[ks][j]);
          sc[ks][j] = (key > qv) ? 0.0625f : e * invd[ks][j];
        }
        s16x4 pk;
        pk[0] = (short)f2bf(sc[ks][0]); pk[1] = (short)f2bf(sc[ks][1]);
        pk[2] = (short)f2bf(sc[ks][2]); pk[3] = (short)f2bf(sc[ks][3]);
        *(s16x4*)&Ws[w][row_l*72 + ks*16 + kgrp*4] = pk;
      }
      // PV (per-wave private Ws: no barrier needed)
      #pragma unroll
      for (int kc = 0; kc < 2; kc++){
        s16x8 af = *(const s16x8*)&Ws[w][row_l*72 + kc*32 + kgrp*8];
        #pragma unroll
        for (int dq = 0; dq < 4; dq++){
          int row = dq*16 + row_l;
          int ev = (row*64 + kc*32 + kgrp*8) ^ ((row & 7) << 3);
          s16x8 vf = *(const s16x8*)&Vst[par][ev];
          pv[dq] = __builtin_amdgcn_mfma_f32_16x16x32_bf16(af, vf, pv[dq], 0, 0, 0);
        }
      }
      __builtin_amdgcn_sched_barrier(0);
      __builtin_amdgcn_s_barrier();
    }

    // epilogue: out rows q = q0 + w*16 + kgrp*4 + j; cols d = dq*16 + row_l
    if (mode == 0){
      int tsuf = qt + 1;
      #pragma unroll
      for (int dq = 0; dq < 4; dq++){
        int d = dq*16 + row_l;
        float suf = sufv[((size_t)(b*16 + h)*33 + tsuf)*64 + d];
        #pragma unroll
        for (int j = 0; j < 4; j++){
          int qo = q0 + w*16 + kgrp*4 + j;
          ab[(size_t)(b*2048 + qo)*1024 + h*64 + d] = f2bf(pv[dq][j] + 0.0625f * suf);
        }
      }
    } else {
      float* pr = pb + ((size_t)((b*16 + h)*16 + i)*2 + (mode - 1)) * 4096;
      #pragma unroll
      for (int dq = 0; dq < 4; dq++){
        int d = dq*16 + row_l;
        #pragma unroll
        for (int j = 0; j < 4; j++)
          pr[(w*16 + kgrp*4 + j)*64 + d] = pv[dq][j];
      }
    }
  };

  if (half == 0){
    run(qsm, 0, i + 1, 0);
    run(qbig, 0, 16 - i, 1);
  } else {
    run(qbig, 16 - i, 32 - i, 2);
  }
}

// ---------------- reduce split partials + suffix tail -> abuf ----------------
__global__ void reduce_kernel(const float* __restrict__ pb,
                              const float* __restrict__ sufv,
                              unsigned short* __restrict__ ab)
{
  int blk = blockIdx.x;               // 512 = (b,h,i)
  int b = blk >> 8, rr = blk & 255;
  int h = rr >> 4, i = rr & 15;
  int qbig = 31 - i, tsuf = 32 - i;
  int t = threadIdx.x;
  int q = t >> 2, dbase = (t & 3) * 16;
  const float* p0 = pb + ((size_t)((b*16 + h)*16 + i)*2 + 0)*4096 + q*64 + dbase;
  const float* p1 = p0 + 4096;
  const float* sf = sufv + ((size_t)(b*16 + h)*33 + tsuf)*64 + dbase;
  unsigned short* op = ab + (size_t)(b*2048 + qbig*64 + q)*1024 + h*64 + dbase;
  #pragma unroll
  for (int e = 0; e < 4; e++){
    float4 a = *(const float4*)(p0 + e*4);
    float4 bb = *(const float4*)(p1 + e*4);
    float4 s = *(const float4*)(sf + e*4);
    unsigned short o[4];
    o[0] = f2bf(a.x + bb.x + 0.0625f * s.x);
    o[1] = f2bf(a.y + bb.y + 0.0625f * s.y);
    o[2] = f2bf(a.z + bb.z + 0.0625f * s.z);
    o[3] = f2bf(a.w + bb.w + 0.0625f * s.w);
    *(s16x4*)(op + e*4) = *(s16x4*)o;
  }
}

// ---------------- host ----------------
extern "C" void kernel_launch(void* const* d_in, const int* in_sizes, int n_in,
                              void* d_out, int out_size, void* d_ws, size_t ws_size,
                              hipStream_t stream) {
  (void)in_sizes; (void)n_in; (void)out_size; (void)ws_size;
  const float* x  = (const float*)d_in[0];
  const float* Wa = (const float*)d_in[1];
  const float* ba = (const float*)d_in[2];
  const float* Wp = (const float*)d_in[3];
  const float* bp = (const float*)d_in[4];
  float* out = (float*)d_out;

  char* ws = (char*)d_ws;
  size_t off = 0;
  auto alloc = [&](size_t bytes) -> void* {
    void* p = ws + off;
    off += (bytes + 255) & ~(size_t)255;
    return p;
  };
  // region A (16 MB): xb (8 MB) + WaT (6 MB) alias pbuf — both dead before pv_kernel writes partials
  float* pbuf          = (float*)alloc((size_t)16*1024*1024);
  unsigned short* xb   = (unsigned short*)((char*)pbuf);
  unsigned short* WaT  = (unsigned short*)((char*)pbuf + (size_t)4096*1024*2);
  unsigned short* WpT  = (unsigned short*)alloc((size_t)1024*1024*2);
  unsigned short* qbuf = (unsigned short*)alloc((size_t)4096*1024*2);
  unsigned short* ktile= (unsigned short*)alloc((size_t)4096*1024*2);
  unsigned short* vtile= (unsigned short*)alloc((size_t)4096*1024*2);
  unsigned short* abuf = (unsigned short*)alloc((size_t)4096*1024*2);
  float* invDT         = (float*)alloc((size_t)2*2048*2048*4);
  float* sufv          = (float*)alloc((size_t)32*33*64*4);

  // 1) conversions
  cvt_kernel<<<2048, 256, 0, stream>>>(x, xb, 4096*1024/8);
  transpose_cvt<<<dim3(3072/32, 1024/32), dim3(32, 8), 0, stream>>>(Wa, WaT, 1024, 3072);
  transpose_cvt<<<dim3(1024/32, 1024/32), dim3(32, 8), 0, stream>>>(Wp, WpT, 1024, 1024);

  // 2) QKV GEMM -> qbuf / ktile / vtile
  gemm_kernel<0><<<dim3(24, 32), 256, 0, stream>>>(xb, WaT, ba, 3072, qbuf, ktile, vtile, nullptr);

  // 3) V suffix sums
  sufv_kernel<<<32, 256, 0, stream>>>(vtile, sufv);

  // 4) denominator pass
  dpass_kernel<<<1056, 256, 0, stream>>>(qbuf, ktile, invDT);

  // 5) PV pass
  pv_kernel<<<1024, 256, 0, stream>>>(qbuf, ktile, vtile, invDT, sufv, abuf, pbuf);

  // 6) reduce split partials
  reduce_kernel<<<512, 256, 0, stream>>>(pbuf, sufv, abuf);

  // 7) projection GEMM
  gemm_kernel<1><<<dim3(8, 32), 256, 0, stream>>>(abuf, WpT, bp, 1024, nullptr, nullptr, nullptr, out);
}

// Round 4
// 177.703 us; speedup vs baseline: 2.2254x; 1.0006x over previous
//
#include <hip/hip_runtime.h>

#define DI __device__ __forceinline__

typedef __attribute__((ext_vector_type(8))) short s16x8;
typedef __attribute__((ext_vector_type(4))) short s16x4;
typedef __attribute__((ext_vector_type(4))) float f32x4;

DI unsigned short f2bf(float f){
  unsigned u = __float_as_uint(f);
  u = (u + 0x7FFFu + ((u >> 16) & 1u)) >> 16;
  return (unsigned short)u;
}
DI float bf2f(unsigned short h){
  return __uint_as_float(((unsigned)h) << 16);
}

DI void gll16(const void* g, void* l){
  __builtin_amdgcn_global_load_lds((const __attribute__((address_space(1))) void*)g,
                                   (__attribute__((address_space(3))) void*)l, 16, 0, 0);
}

// ---------------- elementwise fp32 -> bf16 ----------------
__global__ void cvt_kernel(const float* __restrict__ in, unsigned short* __restrict__ out, int n8){
  int i = blockIdx.x * blockDim.x + threadIdx.x;
  if (i >= n8) return;
  const float4* p = (const float4*)in + (size_t)i * 2;
  float4 a = p[0], b = p[1];
  s16x8 o;
  o[0] = (short)f2bf(a.x); o[1] = (short)f2bf(a.y); o[2] = (short)f2bf(a.z); o[3] = (short)f2bf(a.w);
  o[4] = (short)f2bf(b.x); o[5] = (short)f2bf(b.y); o[6] = (short)f2bf(b.z); o[7] = (short)f2bf(b.w);
  ((s16x8*)out)[i] = o;
}

// ---------------- transpose + convert: in fp32 [R][C] -> out bf16 [C][R] ----------------
__global__ void transpose_cvt(const float* __restrict__ in, unsigned short* __restrict__ out, int R, int C){
  __shared__ float t[32][33];
  int c0 = blockIdx.x * 32, r0 = blockIdx.y * 32;
  int tx = threadIdx.x, ty = threadIdx.y; // 32 x 8
  #pragma unroll
  for (int i = 0; i < 4; i++)
    t[ty + i*8][tx] = in[(size_t)(r0 + ty + i*8) * C + c0 + tx];
  __syncthreads();
  #pragma unroll
  for (int i = 0; i < 4; i++)
    out[(size_t)(c0 + ty + i*8) * R + r0 + tx] = f2bf(t[tx][ty + i*8]);
}

// ---------------- GEMM (m97 structure): C[M x N] = A[M x K] * Wt[N x K]^T + bias ----------------
// global_load_lds width-16 staging; one-bit-per-row XOR swizzle applied to global source chunk
// and to ds_read address (linear LDS dest, rule both-sides-or-neither).
// MODE 0: qkv -> qbuf rows, ktile [b][h][kt64][64k][64d] swz, vtile [b][h][kt64][64d][64k] swz
// MODE 1: proj -> fp32 out
template<int MODE>
__launch_bounds__(256)
__global__ void gemm_kernel(const unsigned short* __restrict__ A,
                            const unsigned short* __restrict__ Wt,
                            const float* __restrict__ bias,
                            int N,
                            unsigned short* __restrict__ qb,
                            unsigned short* __restrict__ kb,
                            unsigned short* __restrict__ vt,
                            float* __restrict__ out)
{
  const int K = 1024;
  __shared__ unsigned short As[128 * 64];
  __shared__ unsigned short Bs[128 * 64];
  int m0 = blockIdx.y * 128, n0 = blockIdx.x * 128;
  int tid = threadIdx.x;
  int lane = tid & 63, w = tid >> 6;
  int row_l = lane & 15, kgrp = lane >> 4;
  int wm = (w >> 1) * 64, wn = (w & 1) * 64;

  // staging: per call c4, wave w stages rows [c4*32+w*8, +8), lane l -> row +l>>3, chunk (l&7)^(l>>3)
  const unsigned short* asrc[4];
  const unsigned short* bsrc[4];
  int ldso[4];
  int chunk = (lane & 7) ^ (lane >> 3);
  #pragma unroll
  for (int c4 = 0; c4 < 4; c4++){
    int r = c4*32 + w*8 + (lane >> 3);
    asrc[c4] = A  + (size_t)(m0 + r) * K + chunk*8;
    bsrc[c4] = Wt + (size_t)(n0 + r) * K + chunk*8;
    ldso[c4] = (c4*32 + w*8) * 64;
  }
  // hoisted swizzled read offsets
  int eA[4], eB[4];
  #pragma unroll
  for (int i = 0; i < 4; i++){
    int ra = wm + i*16 + row_l;
    eA[i] = (ra*64 + kgrp*8) ^ ((ra & 7) << 3);
    int rb = wn + i*16 + row_l;
    eB[i] = (rb*64 + kgrp*8) ^ ((rb & 7) << 3);
  }

  f32x4 acc[4][4];
  #pragma unroll
  for (int i = 0; i < 4; i++)
    #pragma unroll
    for (int j = 0; j < 4; j++)
      acc[i][j] = (f32x4){0.f, 0.f, 0.f, 0.f};

  for (int k0 = 0; k0 < K; k0 += 64){
    #pragma unroll
    for (int c4 = 0; c4 < 4; c4++){
      gll16(asrc[c4] + k0, (void*)(As + ldso[c4]));
      gll16(bsrc[c4] + k0, (void*)(Bs + ldso[c4]));
    }
    __syncthreads();
    #pragma unroll
    for (int kc = 0; kc < 2; kc++){
      s16x8 af[4], bfr[4];
      #pragma unroll
      for (int mi = 0; mi < 4; mi++)
        af[mi] = *(const s16x8*)&As[eA[mi] ^ (kc*32)];
      #pragma unroll
      for (int ni = 0; ni < 4; ni++)
        bfr[ni] = *(const s16x8*)&Bs[eB[ni] ^ (kc*32)];
      #pragma unroll
      for (int mi = 0; mi < 4; mi++)
        #pragma unroll
        for (int ni = 0; ni < 4; ni++)
          acc[mi][ni] = __builtin_amdgcn_mfma_f32_16x16x32_bf16(af[mi], bfr[ni], acc[mi][ni], 0, 0, 0);
    }
    __syncthreads();
  }

  #pragma unroll
  for (int mi = 0; mi < 4; mi++){
    #pragma unroll
    for (int ni = 0; ni < 4; ni++){
      #pragma unroll
      for (int j = 0; j < 4; j++){
        int gr = m0 + wm + mi*16 + kgrp*4 + j;
        int gc = n0 + wn + ni*16 + row_l;
        float v = acc[mi][ni][j] + bias[gc];
        if (MODE == 0){
          int h = gc / 192, cc = gc % 192;
          int b = gr >> 11, s = gr & 2047;
          unsigned short bv = f2bf(v);
          if (cc < 64){
            qb[(size_t)gr * 1024 + h*64 + cc] = bv;
          } else if (cc < 128){
            int d = cc - 64; int kt = s >> 6, kk = s & 63;
            kb[(size_t)((b*16 + h)*32 + kt) * 4096 + ((kk*64 + d) ^ ((kk & 7) << 3))] = bv;
          } else {
            int d = cc - 128; int kt = s >> 6, kk = s & 63;
            vt[(size_t)((b*16 + h)*32 + kt) * 4096 + ((d*64 + kk) ^ ((d & 7) << 3))] = bv;
          }
        } else {
          out[(size_t)gr * N + gc] = v;
        }
      }
    }
  }
}

// ---------------- V suffix sums (64-key granularity): sufv[bh][t in 0..32][64d] ----------------
__global__ void sufv_kernel(const unsigned short* __restrict__ vt, float* __restrict__ sufv){
  __shared__ float tot[4][64];
  int bh = blockIdx.x;                 // 32
  int tid = threadIdx.x;               // 256
  int tq = tid >> 6, d = tid & 63;
  const unsigned short* base = vt + (size_t)bh * 32 * 4096;
  float s[8];
  float run = 0.f;
  for (int j = 7; j >= 0; j--){
    int t = tq*8 + j;
    float rs = 0.f;
    #pragma unroll
    for (int c = 0; c < 8; c++){
      int idx = (d*64 + c*8) ^ ((d & 7) << 3);
      s16x8 v = *(const s16x8*)&base[(size_t)t*4096 + idx];
      #pragma unroll
      for (int e = 0; e < 8; e++) rs += bf2f((unsigned short)v[e]);
    }
    run += rs; s[j] = run;
  }
  tot[tq][d] = run;
  __syncthreads();
  float carry = 0.f;
  for (int t2 = tq+1; t2 < 4; t2++) carry += tot[t2][d];
  #pragma unroll
  for (int j = 0; j < 8; j++)
    sufv[((size_t)bh*33 + tq*8 + j)*64 + d] = s[j] + carry;
  if (tid < 64) sufv[((size_t)bh*33 + 32)*64 + tid] = 0.f;
}

// ---------------- D-pass: invDQ[b][q][k] = 1 / sum_h exp(s_h(q,k)) over causal triangle ----------------
// 2-deep K staging (4 buffers), counted vmcnt, one barrier per head-iteration.
__launch_bounds__(256)
__global__ void dpass_kernel(const unsigned short* __restrict__ qbuf,
                             const unsigned short* __restrict__ kb,
                             float* __restrict__ invDQ)
{
  __shared__ unsigned short Kst[4][4096];
  int blk = blockIdx.x;
  int b = blk / 528, t = blk % 528;
  int qt = (int)((sqrtf(8.f*t + 1.f) - 1.f) * 0.5f);
  while ((qt+1)*(qt+2)/2 <= t) qt++;
  while (qt*(qt+1)/2 > t) qt--;
  int kt = t - qt*(qt+1)/2;

  int tid = threadIdx.x, lane = tid & 63, w = tid >> 6;
  int row_l = lane & 15, kgrp = lane >> 4;

  const unsigned short* ktb = kb + ((size_t)(b*16)*32 + kt) * 4096;
  int sgoff = (w*128 + lane)*8;

  auto stage = [&](int hh, int buf){
    const unsigned short* src = ktb + (size_t)hh * 131072;
    gll16(src + sgoff,       (void*)(&Kst[buf][0] + w*1024));
    gll16(src + sgoff + 512, (void*)(&Kst[buf][0] + w*1024 + 512));
  };

  int e0[4];
  #pragma unroll
  for (int ks = 0; ks < 4; ks++){
    int row = ks*16 + row_l;
    e0[ks] = (row*64 + kgrp*8) ^ ((row & 7) << 3);
  }

  stage(0, 0);
  stage(1, 1);

  f32x4 esum[4];
  #pragma unroll
  for (int ks = 0; ks < 4; ks++) esum[ks] = (f32x4){0.f,0.f,0.f,0.f};

  const unsigned short* qrow_p = qbuf + (size_t)(b*2048 + qt*64 + w*16 + row_l) * 1024;
  s16x8 qf0 = *(const s16x8*)&qrow_p[kgrp*8];
  s16x8 qf1 = *(const s16x8*)&qrow_p[32 + kgrp*8];

  for (int h = 0; h < 16; h++){
    s16x8 qn0, qn1;
    if (h < 15){
      qn0 = *(const s16x8*)&qrow_p[(h+1)*64 + kgrp*8];
      qn1 = *(const s16x8*)&qrow_p[(h+1)*64 + 32 + kgrp*8];
    }
    if (h + 2 < 16) stage(h+2, (h+2) & 3);
    __builtin_amdgcn_sched_barrier(0);
    if (h < 14)      asm volatile("s_waitcnt vmcnt(8)" ::: "memory");
    else if (h < 15) asm volatile("s_waitcnt vmcnt(6)" ::: "memory");
    else             asm volatile("s_waitcnt vmcnt(2)" ::: "memory");
    __builtin_amdgcn_sched_barrier(0);
    __builtin_amdgcn_s_barrier();
    __builtin_amdgcn_sched_barrier(0);

    const unsigned short* kl = &Kst[h & 3][0];
    #pragma unroll
    for (int ks = 0; ks < 4; ks++){
      s16x8 a0 = *(const s16x8*)&kl[e0[ks]];
      s16x8 a1 = *(const s16x8*)&kl[e0[ks] ^ 32];
      f32x4 sc = __builtin_amdgcn_mfma_f32_16x16x32_bf16(a0, qf0, (f32x4){0.f,0.f,0.f,0.f}, 0, 0, 0);
      sc = __builtin_amdgcn_mfma_f32_16x16x32_bf16(a1, qf1, sc, 0, 0, 0);
      #pragma unroll
      for (int j = 0; j < 4; j++) esum[ks][j] += __expf(sc[j]);
    }
    if (h < 15){ qf0 = qn0; qf1 = qn1; }
  }

  int qcol = qt*64 + w*16 + row_l;
  float* dst = invDQ + (size_t)b*4194304 + (size_t)qcol*2048 + kt*64 + kgrp*4;
  #pragma unroll
  for (int ks = 0; ks < 4; ks++){
    f32x4 rv;
    #pragma unroll
    for (int j = 0; j < 4; j++) rv[j] = 1.f / esum[ks][j];
    *(f32x4*)&dst[ks*16] = rv;
  }
}

// ---------------- PV-pass: per (b,h), w = exp(s)*invD (masked -> 1/16 via suffix), O = w @ V ----------------
// 2-deep K/V staging (4 buffers each), invD prefetched 1 tile ahead in regs, cvt_pk packing,
// one barrier per k-tile. grid 1024 = (b, h, pair i, half).
__launch_bounds__(256)
__global__ void pv_kernel(const unsigned short* __restrict__ qbuf,
                          const unsigned short* __restrict__ kb,
                          const unsigned short* __restrict__ vt,
                          const float* __restrict__ invDQ,
                          const float* __restrict__ sufv,
                          unsigned short* __restrict__ ab,
                          float* __restrict__ pb)
{
  extern __shared__ unsigned short lds[];
  unsigned short* KstB = lds;            // 4 x 4096
  unsigned short* VstB = lds + 16384;    // 4 x 4096
  unsigned short* WsB  = lds + 32768;    // 4 x 1152 (per-wave private)

  int blk = blockIdx.x;
  int b = blk >> 9;
  int r = blk & 511;
  int h = r >> 5;
  int r2 = r & 31;
  int i = r2 >> 1, half = r2 & 1;
  int qsm = i, qbig = 31 - i;

  int tid = threadIdx.x, lane = tid & 63, w = tid >> 6;
  int row_l = lane & 15, kgrp = lane >> 4;

  const unsigned short* KT = kb + (size_t)((b*16 + h)*32) * 4096;
  const unsigned short* VT = vt + (size_t)((b*16 + h)*32) * 4096;
  int sgoff = (w*128 + lane)*8;
  unsigned short* Wsw = WsB + w*1152;

  int eK[4];
  #pragma unroll
  for (int ks = 0; ks < 4; ks++){
    int row = ks*16 + row_l;
    eK[ks] = (row*64 + kgrp*8) ^ ((row & 7) << 3);
  }

  auto stage = [&](int kt, int buf){
    gll16(KT + (size_t)kt*4096 + sgoff,       (void*)(KstB + buf*4096 + w*1024));
    gll16(KT + (size_t)kt*4096 + sgoff + 512, (void*)(KstB + buf*4096 + w*1024 + 512));
    gll16(VT + (size_t)kt*4096 + sgoff,       (void*)(VstB + buf*4096 + w*1024));
    gll16(VT + (size_t)kt*4096 + sgoff + 512, (void*)(VstB + buf*4096 + w*1024 + 512));
  };

  auto run = [&](int qt, int k0t, int k1t, int mode){
    int q0 = qt * 64;
    int qv = q0 + w*16 + row_l;
    const unsigned short* qrow_p = qbuf + (size_t)(b*2048 + qv) * 1024 + h*64;
    s16x8 qf0 = *(const s16x8*)&qrow_p[kgrp*8];
    s16x8 qf1 = *(const s16x8*)&qrow_p[32 + kgrp*8];
    const float* ivrow = invDQ + (size_t)b*4194304 + (size_t)qv*2048 + kgrp*4;

    f32x4 pvv[4];
    #pragma unroll
    for (int d = 0; d < 4; d++) pvv[d] = (f32x4){0.f,0.f,0.f,0.f};

    // prologue: stage(k0t) BEFORE invd loads (in-order retirement => invd wait drains stage(k0t))
    stage(k0t, 0);
    f32x4 inxt[4];
    #pragma unroll
    for (int ks = 0; ks < 4; ks++) inxt[ks] = *(const f32x4*)&ivrow[k0t*64 + ks*16];
    if (k0t + 1 < k1t) stage(k0t+1, 1);

    for (int kt = k0t; kt < k1t; kt++){
      int par = (kt - k0t) & 3;
      f32x4 icur[4];
      #pragma unroll
      for (int ks = 0; ks < 4; ks++) icur[ks] = inxt[ks];
      if (kt + 1 < k1t){
        #pragma unroll
        for (int ks = 0; ks < 4; ks++) inxt[ks] = *(const f32x4*)&ivrow[(kt+1)*64 + ks*16];
      }
      if (kt + 2 < k1t) stage(kt+2, (par + 2) & 3);
      __builtin_amdgcn_sched_barrier(0);
      if (kt + 2 < k1t)      asm volatile("s_waitcnt vmcnt(16)" ::: "memory");
      else if (kt + 1 < k1t) asm volatile("s_waitcnt vmcnt(12)" ::: "memory");
      else                   asm volatile("s_waitcnt vmcnt(4)" ::: "memory");
      __builtin_amdgcn_sched_barrier(0);
      __builtin_amdgcn_s_barrier();
      __builtin_amdgcn_sched_barrier(0);

      const unsigned short* kl = KstB + par*4096;
      const unsigned short* vl = VstB + par*4096;
      // QK^T (swapped: rows=key, cols=q)
      f32x4 sc[4];
      #pragma unroll
      for (int ks = 0; ks < 4; ks++){
        s16x8 a0 = *(const s16x8*)&kl[eK[ks]];
        s16x8 a1 = *(const s16x8*)&kl[eK[ks] ^ 32];
        sc[ks] = __builtin_amdgcn_mfma_f32_16x16x32_bf16(a0, qf0, (f32x4){0.f,0.f,0.f,0.f}, 0, 0, 0);
        sc[ks] = __builtin_amdgcn_mfma_f32_16x16x32_bf16(a1, qf1, sc[ks], 0, 0, 0);
      }
      // weights + packed b64 writes
      int kbase = kt*64 + kgrp*4;
      #pragma unroll
      for (int ks = 0; ks < 4; ks++){
        #pragma unroll
        for (int j = 0; j < 4; j++){
          float e = __expf(sc[ks][j]);
          sc[ks][j] = (kbase + ks*16 + j > qv) ? 0.0625f : e * icur[ks][j];
        }
        unsigned lo, hi;
        asm("v_cvt_pk_bf16_f32 %0, %1, %2" : "=v"(lo) : "v"(sc[ks][0]), "v"(sc[ks][1]));
        asm("v_cvt_pk_bf16_f32 %0, %1, %2" : "=v"(hi) : "v"(sc[ks][2]), "v"(sc[ks][3]));
        uint2 pk2; pk2.x = lo; pk2.y = hi;
        *(uint2*)&Wsw[row_l*72 + ks*16 + kgrp*4] = pk2;
      }
      // PV (per-wave private Ws: no barrier needed)
      #pragma unroll
      for (int kc = 0; kc < 2; kc++){
        s16x8 af = *(const s16x8*)&Wsw[row_l*72 + kc*32 + kgrp*8];
        #pragma unroll
        for (int dq = 0; dq < 4; dq++){
          s16x8 vf = *(const s16x8*)&vl[eK[dq] ^ (kc*32)];
          pvv[dq] = __builtin_amdgcn_mfma_f32_16x16x32_bf16(af, vf, pvv[dq], 0, 0, 0);
        }
      }
    }

    // epilogue: out rows q = q0 + w*16 + kgrp*4 + j; cols d = dq*16 + row_l
    if (mode == 0){
      int tsuf = qt + 1;
      #pragma unroll
      for (int dq = 0; dq < 4; dq++){
        int d = dq*16 + row_l;
        float suf = sufv[((size_t)(b*16 + h)*33 + tsuf)*64 + d];
        #pragma unroll
        for (int j = 0; j < 4; j++){
          int qo = q0 + w*16 + kgrp*4 + j;
          ab[(size_t)(b*2048 + qo)*1024 + h*64 + d] = f2bf(pvv[dq][j] + 0.0625f * suf);
        }
      }
    } else {
      float* pr = pb + ((size_t)((b*16 + h)*16 + i)*2 + (mode - 1)) * 4096;
      #pragma unroll
      for (int dq = 0; dq < 4; dq++){
        int d = dq*16 + row_l;
        #pragma unroll
        for (int j = 0; j < 4; j++)
          pr[(w*16 + kgrp*4 + j)*64 + d] = pvv[dq][j];
      }
    }
  };

  if (half == 0){
    run(qsm, 0, i + 1, 0);
    run(qbig, 0, 16 - i, 1);
  } else {
    run(qbig, 16 - i, 32 - i, 2);
  }
}

// ---------------- reduce split partials + suffix tail -> abuf ----------------
__global__ void reduce_kernel(const float* __restrict__ pb,
                              const float* __restrict__ sufv,
                              unsigned short* __restrict__ ab)
{
  int blk = blockIdx.x;               // 512 = (b,h,i)
  int b = blk >> 8, rr = blk & 255;
  int h = rr >> 4, i = rr & 15;
  int qbig = 31 - i, tsuf = 32 - i;
  int t = threadIdx.x;
  int q = t >> 2, dbase = (t & 3) * 16;
  const float* p0 = pb + ((size_t)((b*16 + h)*16 + i)*2 + 0)*4096 + q*64 + dbase;
  const float* p1 = p0 + 4096;
  const float* sf = sufv + ((size_t)(b*16 + h)*33 + tsuf)*64 + dbase;
  unsigned short* op = ab + (size_t)(b*2048 + qbig*64 + q)*1024 + h*64 + dbase;
  #pragma unroll
  for (int e = 0; e < 4; e++){
    float4 a = *(const float4*)(p0 + e*4);
    float4 bb = *(const float4*)(p1 + e*4);
    float4 s = *(const float4*)(sf + e*4);
    unsigned short o[4];
    o[0] = f2bf(a.x + bb.x + 0.0625f * s.x);
    o[1] = f2bf(a.y + bb.y + 0.0625f * s.y);
    o[2] = f2bf(a.z + bb.z + 0.0625f * s.z);
    o[3] = f2bf(a.w + bb.w + 0.0625f * s.w);
    *(s16x4*)(op + e*4) = *(s16x4*)o;
  }
}

// ---------------- host ----------------
extern "C" void kernel_launch(void* const* d_in, const int* in_sizes, int n_in,
                              void* d_out, int out_size, void* d_ws, size_t ws_size,
                              hipStream_t stream) {
  (void)in_sizes; (void)n_in; (void)out_size; (void)ws_size;
  const float* x  = (const float*)d_in[0];
  const float* Wa = (const float*)d_in[1];
  const float* ba = (const float*)d_in[2];
  const float* Wp = (const float*)d_in[3];
  const float* bp = (const float*)d_in[4];
  float* out = (float*)d_out;

  char* ws = (char*)d_ws;
  size_t off = 0;
  auto alloc = [&](size_t bytes) -> void* {
    void* p = ws + off;
    off += (bytes + 255) & ~(size_t)255;
    return p;
  };
  // region A (16 MB): xb (8 MB) + WaT (6 MB) alias pbuf — both dead before pv_kernel writes partials
  float* pbuf          = (float*)alloc((size_t)16*1024*1024);
  unsigned short* xb   = (unsigned short*)((char*)pbuf);
  unsigned short* WaT  = (unsigned short*)((char*)pbuf + (size_t)4096*1024*2);
  unsigned short* WpT  = (unsigned short*)alloc((size_t)1024*1024*2);
  unsigned short* qbuf = (unsigned short*)alloc((size_t)4096*1024*2);
  unsigned short* ktile= (unsigned short*)alloc((size_t)4096*1024*2);
  unsigned short* vtile= (unsigned short*)alloc((size_t)4096*1024*2);
  unsigned short* abuf = (unsigned short*)alloc((size_t)4096*1024*2);
  float* invDQ         = (float*)alloc((size_t)2*2048*2048*4);
  float* sufv          = (float*)alloc((size_t)32*33*64*4);

  // 1) conversions
  cvt_kernel<<<2048, 256, 0, stream>>>(x, xb, 4096*1024/8);
  transpose_cvt<<<dim3(3072/32, 1024/32), dim3(32, 8), 0, stream>>>(Wa, WaT, 1024, 3072);
  transpose_cvt<<<dim3(1024/32, 1024/32), dim3(32, 8), 0, stream>>>(Wp, WpT, 1024, 1024);

  // 2) QKV GEMM -> qbuf / ktile / vtile
  gemm_kernel<0><<<dim3(24, 32), 256, 0, stream>>>(xb, WaT, ba, 3072, qbuf, ktile, vtile, nullptr);

  // 3) V suffix sums
  sufv_kernel<<<32, 256, 0, stream>>>(vtile, sufv);

  // 4) denominator pass
  dpass_kernel<<<1056, 256, 0, stream>>>(qbuf, ktile, invDQ);

  // 5) PV pass
  static int smem_set = 0;
  size_t smem = (size_t)(16384 + 16384 + 4608) * sizeof(unsigned short); // 74752 B
  if (!smem_set) {
    hipFuncSetAttribute(reinterpret_cast<const void*>(pv_kernel),
                        hipFuncAttributeMaxDynamicSharedMemorySize, (int)smem);
    smem_set = 1;
  }
  pv_kernel<<<1024, 256, smem, stream>>>(qbuf, ktile, vtile, invDQ, sufv, abuf, pbuf);

  // 6) reduce split partials
  reduce_kernel<<<512, 256, 0, stream>>>(pbuf, sufv, abuf);

  // 7) projection GEMM
  gemm_kernel<1><<<dim3(8, 32), 256, 0, stream>>>(abuf, WpT, bp, 1024, nullptr, nullptr, nullptr, out);
}